// Round 1
// baseline (592.149 us; speedup 1.0000x reference)
//
#include <hip/hip_runtime.h>

#define D_DIM 128
#define NEG_SLOPE 0.2f

// One row of Wx_i/Wx_j is 128 floats = 32 float4.
// 32 lanes per row, each lane: 1 float4 from each matrix (16B/lane coalesced).
// Wave (64 lanes) covers 2 adjacent rows -> 1KB contiguous read per matrix.
// Block 256 threads -> 8 rows/block.
__global__ __launch_bounds__(256) void gat_score_kernel(
    const float* __restrict__ Wx_i,
    const float* __restrict__ Wx_j,
    const float* __restrict__ a,
    float* __restrict__ out,
    int E)
{
    const int tid = threadIdx.x;
    const int lane32 = tid & 31;       // slot within the row (0..31)
    const int rowInBlock = tid >> 5;   // 0..7
    const int row = blockIdx.x * 8 + rowInBlock;

    // Per-lane slice of the attention vector (cached in registers; a is 1KB total)
    const float4 as = ((const float4*)a)[lane32];           // a_src[4*lane32 .. +3]
    const float4 ad = ((const float4*)(a + D_DIM))[lane32]; // a_dst[4*lane32 .. +3]

    if (row < E) {
        const float4 xi = ((const float4*)(Wx_i + (size_t)row * D_DIM))[lane32];
        const float4 xj = ((const float4*)(Wx_j + (size_t)row * D_DIM))[lane32];

        float s = xi.x * as.x + xi.y * as.y + xi.z * as.z + xi.w * as.w
                + xj.x * ad.x + xj.y * ad.y + xj.z * ad.z + xj.w * ad.w;

        // Reduce across the 32 lanes owning this row
        #pragma unroll
        for (int off = 16; off > 0; off >>= 1)
            s += __shfl_down(s, off, 32);

        if (lane32 == 0)
            out[row] = (s > 0.0f) ? s : NEG_SLOPE * s;
    }
}

extern "C" void kernel_launch(void* const* d_in, const int* in_sizes, int n_in,
                              void* d_out, int out_size, void* d_ws, size_t ws_size,
                              hipStream_t stream) {
    const float* Wx_i = (const float*)d_in[0];
    const float* Wx_j = (const float*)d_in[1];
    const float* a    = (const float*)d_in[2];
    float* out = (float*)d_out;

    const int E = out_size;               // 640000 rows
    const int rowsPerBlock = 8;           // 256 threads / 32 lanes-per-row
    const int grid = (E + rowsPerBlock - 1) / rowsPerBlock;

    gat_score_kernel<<<grid, 256, 0, stream>>>(Wx_i, Wx_j, a, out, E);
}